// Round 1
// baseline (659.283 us; speedup 1.0000x reference)
//
#include <hip/hip_runtime.h>

#define S 128
#define L (S*S)
#define AK 21
#define AC 2
#define PP 882          // AC*AK*AK
#define HX 148          // S + AK - 1
#define LK 41
#define KK 1681         // LK*LK
#define EX 9
#define MAXR 19
#define NITER 5

// ---------- helpers ----------

__device__ __forceinline__ int reflect_idx(int i) {
  i = (i < 0) ? -i : i;
  return (i >= S) ? (2 * S - 2 - i) : i;
}

__device__ __forceinline__ void wave_red2(float& a, float& b) {
#pragma unroll
  for (int o = 32; o; o >>= 1) {
    a += __shfl_down(a, o);
    b += __shfl_down(b, o);
  }
}

// ---------- K1: x_tiles + raw_aff + aff + initial lat + zero mean ----------
// one wave per pixel l; lanes stride over p in [0, 882)
__global__ void k_xtiles(const float* __restrict__ x,
                         const float* __restrict__ rfs,
                         const float* __restrict__ adath,
                         const float* __restrict__ aenv,
                         float* __restrict__ out_raw,   // d_out + 0
                         float* __restrict__ out_xt,    // d_out + 32769
                         float* __restrict__ aff,
                         float* __restrict__ latA,
                         float* __restrict__ mean) {
  int wid = (blockIdx.x * blockDim.x + threadIdx.x) >> 6;
  int lane = threadIdx.x & 63;
  if (wid >= L) return;
  int i = wid >> 7, j = wid & (S - 1);
  const float* rrow = rfs + (size_t)wid * PP;
  float* xrow = out_xt + (size_t)wid * PP;
  float accd = 0.f, accs = 0.f;
  for (int p = lane; p < PP; p += 64) {
    int c = (p >= 441) ? 1 : 0;
    int r = p - c * 441;
    int kh = r / 21;
    int kw = r - kh * 21;
    float xv = x[c * (HX * HX) + (i + kh) * HX + (j + kw)];
    float xt = xv * aenv[p];
    xrow[p] = xt;
    float w = rrow[p];
    accd += xt * w;
    accs += w;
  }
  wave_red2(accd, accs);
  if (lane == 0) {
    out_raw[wid] = accd * ((float)PP / accs);
    float a = accd / accs - adath[wid];
    aff[wid] = a;
    latA[wid] = a > 0.f ? a : 0.f;
    mean[wid] = 0.f;
  }
}

// ---------- K2: 9x9 reflect-pad convolution ----------
__global__ void k_conv(const float* __restrict__ latA,
                       const float* __restrict__ sre,
                       float* __restrict__ latC) {
  int l = blockIdx.x * blockDim.x + threadIdx.x;
  if (l >= L) return;
  int i = l >> 7, j = l & (S - 1);
  float acc = 0.f;
#pragma unroll
  for (int u = 0; u < EX; ++u) {
    int ii = reflect_idx(i + u - EX / 2);
#pragma unroll
    for (int v = 0; v < EX; ++v) {
      int jj = reflect_idx(j + v - EX / 2);
      acc += latA[ii * S + jj] * sre[u * EX + v];
    }
  }
  latC[l] = acc;
}

// ---------- K3: lat_neg (41x41 weighted, zero-pad) + update ----------
// one wave per pixel; lanes stride over k in [0, 1681)
__global__ void k_latneg(const float* __restrict__ lw,
                         const float* __restrict__ envk,
                         const float* __restrict__ latC,
                         const float* __restrict__ aff,
                         float* __restrict__ lat2) {
  int wid = (blockIdx.x * blockDim.x + threadIdx.x) >> 6;
  int lane = threadIdx.x & 63;
  if (wid >= L) return;
  int i = wid >> 7, j = wid & (S - 1);
  const float* wrow = lw + (size_t)wid * KK;
  float accn = 0.f, accw = 0.f;
  for (int k = lane; k < KK; k += 64) {
    float w = wrow[k];
    accw += w;
    int kh = k / LK;
    int kw = k - kh * LK;
    int ii = i + kh - LK / 2;
    int jj = j + kw - LK / 2;
    float pv = 0.f;
    if ((unsigned)ii < (unsigned)S && (unsigned)jj < (unsigned)S)
      pv = latC[ii * S + jj];
    accn += w * envk[k] * pv;
  }
  wave_red2(accn, accw);
  if (lane == 0) {
    float ln = accn / accw;           // lat_neg (already includes /K via /wsum)
    float v = latC[wid] - ln + aff[wid];
    lat2[wid] = (v > 0.f ? v : 0.f) * 1.5f;
  }
}

// ---------- K4: 19x19 masked max (reflect) + normalize + mean accum ----------
__global__ void k_maxnorm(const float* __restrict__ lat2,
                          const float* __restrict__ mmask,
                          float* __restrict__ latA,
                          float* __restrict__ mean,
                          float* __restrict__ out_lat,
                          int last) {
  int l = blockIdx.x * blockDim.x + threadIdx.x;
  if (l >= L) return;
  int i = l >> 7, j = l & (S - 1);
  float m = 1.0f;
#pragma unroll
  for (int u = 0; u < MAXR; ++u) {
    int ii = reflect_idx(i + u - MAXR / 2);
#pragma unroll 1
    for (int v = 0; v < MAXR; ++v) {
      float mv = mmask[u * MAXR + v];
      int jj = reflect_idx(j + v - MAXR / 2);
      float val = lat2[ii * S + jj] * mv;
      m = fmaxf(m, val);
    }
  }
  float lv = lat2[l] / (m + 1e-5f);
  latA[l] = lv;
  mean[l] += lv;
  if (last) out_lat[l] = lv;
}

// ---------- K5: correlation partials (per pixel) ----------
__global__ void k_corrpart(const float* __restrict__ lw,
                           const float* __restrict__ envk,
                           const float* __restrict__ mean,
                           float* __restrict__ part) {
  int wid = (blockIdx.x * blockDim.x + threadIdx.x) >> 6;
  int lane = threadIdx.x & 63;
  if (wid >= L) return;
  int i = wid >> 7, j = wid & (S - 1);
  const float* wrow = lw + (size_t)wid * KK;
  float accn = 0.f, accw = 0.f;
  const float inv_it = 1.0f / (float)NITER;
  for (int k = lane; k < KK; k += 64) {
    float w = wrow[k];
    accw += w;
    int kh = k / LK;
    int kw = k - kh * LK;
    int ii = i + kh - LK / 2;
    int jj = j + kw - LK / 2;
    float pv = 0.f;
    if ((unsigned)ii < (unsigned)S && (unsigned)jj < (unsigned)S)
      pv = mean[ii * S + jj] * inv_it;
    accn += w * envk[k] * pv;
  }
  wave_red2(accn, accw);
  if (lane == 0) {
    float lm = mean[wid] * inv_it;
    // contrib = lat_mean[l] * (K / wsum[l]) * sum_k patch*env*w
    part[wid] = lm * ((float)KK / accw) * accn;
  }
}

// ---------- K6: final reduce of 16384 partials -> scalar ----------
__global__ void k_reduce(const float* __restrict__ part,
                         float* __restrict__ out) {
  float a = 0.f;
  for (int idx = threadIdx.x; idx < L; idx += 256) a += part[idx];
#pragma unroll
  for (int o = 32; o; o >>= 1) a += __shfl_down(a, o);
  __shared__ float sm[4];
  if ((threadIdx.x & 63) == 0) sm[threadIdx.x >> 6] = a;
  __syncthreads();
  if (threadIdx.x == 0) out[0] = sm[0] + sm[1] + sm[2] + sm[3];
}

// ---------- launch ----------
extern "C" void kernel_launch(void* const* d_in, const int* in_sizes, int n_in,
                              void* d_out, int out_size, void* d_ws, size_t ws_size,
                              hipStream_t stream) {
  const float* x     = (const float*)d_in[0];
  const float* rfs   = (const float*)d_in[1];
  const float* lw    = (const float*)d_in[2];
  const float* adath = (const float*)d_in[3];
  const float* aenv  = (const float*)d_in[4];
  const float* sre   = (const float*)d_in[5];
  const float* envk  = (const float*)d_in[6];
  const float* mmask = (const float*)d_in[7];

  float* out = (float*)d_out;
  float* out_raw = out;            // 16384
  float* out_lat = out + L;        // 16384
  float* out_cor = out + 2 * L;    // 1
  float* out_xt  = out + 2 * L + 1;// 16384*882

  float* wsf  = (float*)d_ws;
  float* aff  = wsf;
  float* latA = wsf + L;
  float* latC = wsf + 2 * L;
  float* lat2 = wsf + 3 * L;
  float* mean = wsf + 4 * L;
  float* part = wsf + 5 * L;

  dim3 blk(256);
  dim3 grid_wave(L / 4);   // wave-per-pixel kernels: 4 waves/block
  dim3 grid_px(L / 256);   // thread-per-pixel kernels

  k_xtiles<<<grid_wave, blk, 0, stream>>>(x, rfs, adath, aenv,
                                          out_raw, out_xt, aff, latA, mean);
  for (int it = 0; it < NITER; ++it) {
    k_conv<<<grid_px, blk, 0, stream>>>(latA, sre, latC);
    k_latneg<<<grid_wave, blk, 0, stream>>>(lw, envk, latC, aff, lat2);
    k_maxnorm<<<grid_px, blk, 0, stream>>>(lat2, mmask, latA, mean, out_lat,
                                           (it == NITER - 1) ? 1 : 0);
  }
  k_corrpart<<<grid_wave, blk, 0, stream>>>(lw, envk, mean, part);
  k_reduce<<<1, blk, 0, stream>>>(part, out_cor);
}

// Round 2
// 565.675 us; speedup vs baseline: 1.1655x; 1.1655x over previous
//
#include <hip/hip_runtime.h>

#define S 128
#define L (S*S)
#define AK 21
#define AC 2
#define PP 882          // AC*AK*AK
#define HX 148          // S + AK - 1
#define LK 41
#define KK 1681         // LK*LK
#define EX 9
#define MAXR 19
#define NITER 5

// ---------- helpers ----------

__device__ __forceinline__ int reflect_idx(int i) {
  i = (i < 0) ? -i : i;
  return (i >= S) ? (2 * S - 2 - i) : i;
}

__device__ __forceinline__ void wave_red2(float& a, float& b) {
#pragma unroll
  for (int o = 32; o; o >>= 1) {
    a += __shfl_down(a, o);
    b += __shfl_down(b, o);
  }
}

__device__ __forceinline__ float gmap(const float* __restrict__ m,
                                      int i, int j, int kh, int kw) {
  int ii = i + kh - LK / 2;
  int jj = j + kw - LK / 2;
  return ((unsigned)ii < (unsigned)S && (unsigned)jj < (unsigned)S)
             ? m[ii * S + jj] : 0.f;
}

// Core: per-pixel scan of one lat_weights row (1681 elems), accumulating
// accn = sum w*env*map(patch)  and  accw = sum w.  float4 main loop with
// per-row alignment prologue (row start element offset = wid*1681, mod 4 = wid mod 4).
__device__ __forceinline__ void row_scan(const float* __restrict__ lw,
                                         const float* __restrict__ envk,
                                         const float* __restrict__ m,
                                         int wid, int lane,
                                         float& accn, float& accw) {
  int i = wid >> 7, j = wid & (S - 1);
  const float* wrow = lw + (size_t)wid * KK;
  const int pro = (4 - (wid & 3)) & 3;         // elems to 16B boundary
  const int n4 = (KK - pro) >> 2;              // full float4s
  const int tail = (KK - pro) & 3;
  accn = 0.f; accw = 0.f;
  // prologue
  if (lane < pro) {
    int k = lane;
    float w = wrow[k];
    int kh = k / LK, kw = k - kh * LK;
    accw += w;
    accn += w * envk[k] * gmap(m, i, j, kh, kw);
  }
  // main float4 loop
  const float4* wrow4 = (const float4*)(wrow + pro);
  for (int q = lane; q < n4; q += 64) {
    float4 w4 = wrow4[q];
    int k0 = pro + (q << 2);
    int kh = k0 / LK;
    int kw = k0 - kh * LK;
    accw += (w4.x + w4.y) + (w4.z + w4.w);
    float a;
    a = w4.x * envk[k0]     * gmap(m, i, j, kh, kw);
    kw++; if (kw >= LK) { kw -= LK; kh++; }
    a += w4.y * envk[k0 + 1] * gmap(m, i, j, kh, kw);
    kw++; if (kw >= LK) { kw -= LK; kh++; }
    a += w4.z * envk[k0 + 2] * gmap(m, i, j, kh, kw);
    kw++; if (kw >= LK) { kw -= LK; kh++; }
    a += w4.w * envk[k0 + 3] * gmap(m, i, j, kh, kw);
    accn += a;
  }
  // tail
  if (lane < tail) {
    int k = pro + (n4 << 2) + lane;
    float w = wrow[k];
    int kh = k / LK, kw = k - kh * LK;
    accw += w;
    accn += w * envk[k] * gmap(m, i, j, kh, kw);
  }
  wave_red2(accn, accw);
}

// ---------- K1: x_tiles + raw_aff + aff + initial lat + zero mean ----------
// one wave per pixel; float2 loads (rows are 8B aligned: 882*4 = 3528 = 8*441)
__global__ void k_xtiles(const float* __restrict__ x,
                         const float* __restrict__ rfs,
                         const float* __restrict__ adath,
                         const float* __restrict__ aenv,
                         float* __restrict__ out_raw,
                         float* __restrict__ out_xt,
                         float* __restrict__ aff,
                         float* __restrict__ latA,
                         float* __restrict__ mean) {
  int wid = (blockIdx.x * blockDim.x + threadIdx.x) >> 6;
  int lane = threadIdx.x & 63;
  if (wid >= L) return;
  int i = wid >> 7, j = wid & (S - 1);
  const float2* rrow2 = (const float2*)(rfs + (size_t)wid * PP);
  float2* xrow2 = (float2*)(out_xt + (size_t)wid * PP);
  const float2* aenv2 = (const float2*)aenv;
  float accd = 0.f, accs = 0.f;
  for (int q = lane; q < PP / 2; q += 64) {
    float2 w2 = rrow2[q];
    float2 e2 = aenv2[q];
    int p0 = q << 1;
    // element p0
    int c = (p0 >= 441) ? 1 : 0;
    int r = p0 - c * 441;
    int kh = r / AK, kw = r - kh * AK;
    float xt0 = x[c * (HX * HX) + (i + kh) * HX + (j + kw)] * e2.x;
    // element p0+1
    int p1 = p0 + 1;
    int c1 = (p1 >= 441) ? 1 : 0;
    int r1 = p1 - c1 * 441;
    int kh1 = r1 / AK, kw1 = r1 - kh1 * AK;
    float xt1 = x[c1 * (HX * HX) + (i + kh1) * HX + (j + kw1)] * e2.y;
    xrow2[q] = make_float2(xt0, xt1);
    accd += xt0 * w2.x + xt1 * w2.y;
    accs += w2.x + w2.y;
  }
  wave_red2(accd, accs);
  if (lane == 0) {
    out_raw[wid] = accd * ((float)PP / accs);
    float a = accd / accs - adath[wid];
    aff[wid] = a;
    latA[wid] = a > 0.f ? a : 0.f;
    mean[wid] = 0.f;
  }
}

// ---------- K2: 9x9 reflect-pad convolution (wave per pixel) ----------
__global__ void k_conv(const float* __restrict__ latA,
                       const float* __restrict__ sre,
                       float* __restrict__ latC) {
  int wid = (blockIdx.x * blockDim.x + threadIdx.x) >> 6;
  int lane = threadIdx.x & 63;
  if (wid >= L) return;
  int i = wid >> 7, j = wid & (S - 1);
  float acc = 0.f;
#pragma unroll
  for (int t0 = 0; t0 < 2; ++t0) {
    int t = t0 * 64 + lane;
    if (t < EX * EX) {
      int u = t / EX, v = t - u * EX;
      int ii = reflect_idx(i + u - EX / 2);
      int jj = reflect_idx(j + v - EX / 2);
      acc += latA[ii * S + jj] * sre[t];
    }
  }
#pragma unroll
  for (int o = 32; o; o >>= 1) acc += __shfl_xor(acc, o);
  if (lane == 0) latC[wid] = acc;
}

// ---------- K3: lat_neg + update (wave per pixel, float4 stream) ----------
__global__ void k_latneg(const float* __restrict__ lw,
                         const float* __restrict__ envk,
                         const float* __restrict__ latC,
                         const float* __restrict__ aff,
                         float* __restrict__ lat2) {
  int wid = (blockIdx.x * blockDim.x + threadIdx.x) >> 6;
  int lane = threadIdx.x & 63;
  if (wid >= L) return;
  float accn, accw;
  row_scan(lw, envk, latC, wid, lane, accn, accw);
  if (lane == 0) {
    float ln = accn / accw;
    float v = latC[wid] - ln + aff[wid];
    lat2[wid] = (v > 0.f ? v : 0.f) * 1.5f;
  }
}

// ---------- K4: 19x19 masked max + normalize + mean accum (wave per pixel) ----------
__global__ void k_maxnorm(const float* __restrict__ lat2,
                          const float* __restrict__ mmask,
                          float* __restrict__ latA,
                          float* __restrict__ mean,
                          float* __restrict__ out_lat,
                          int last) {
  int wid = (blockIdx.x * blockDim.x + threadIdx.x) >> 6;
  int lane = threadIdx.x & 63;
  if (wid >= L) return;
  int i = wid >> 7, j = wid & (S - 1);
  float m = 1.0f;
#pragma unroll
  for (int t0 = 0; t0 < 6; ++t0) {
    int t = t0 * 64 + lane;
    if (t < MAXR * MAXR) {
      int u = t / MAXR, v = t - u * MAXR;
      int ii = reflect_idx(i + u - MAXR / 2);
      int jj = reflect_idx(j + v - MAXR / 2);
      m = fmaxf(m, lat2[ii * S + jj] * mmask[t]);
    }
  }
#pragma unroll
  for (int o = 32; o; o >>= 1) m = fmaxf(m, __shfl_xor(m, o));
  if (lane == 0) {
    float lv = lat2[wid] / (m + 1e-5f);
    latA[wid] = lv;
    mean[wid] += lv;
    if (last) out_lat[wid] = lv;
  }
}

// ---------- K5: correlation partials ----------
__global__ void k_corrpart(const float* __restrict__ lw,
                           const float* __restrict__ envk,
                           const float* __restrict__ mean,
                           float* __restrict__ part) {
  int wid = (blockIdx.x * blockDim.x + threadIdx.x) >> 6;
  int lane = threadIdx.x & 63;
  if (wid >= L) return;
  float accn, accw;
  row_scan(lw, envk, mean, wid, lane, accn, accw);
  if (lane == 0) {
    const float inv_it = 1.0f / (float)NITER;
    float lm = mean[wid] * inv_it;
    part[wid] = lm * ((float)KK / accw) * (accn * inv_it);
  }
}

// ---------- K6: final reduce ----------
__global__ void k_reduce(const float* __restrict__ part,
                         float* __restrict__ out) {
  float a = 0.f;
  for (int idx = threadIdx.x; idx < L; idx += 256) a += part[idx];
#pragma unroll
  for (int o = 32; o; o >>= 1) a += __shfl_down(a, o);
  __shared__ float sm[4];
  if ((threadIdx.x & 63) == 0) sm[threadIdx.x >> 6] = a;
  __syncthreads();
  if (threadIdx.x == 0) out[0] = sm[0] + sm[1] + sm[2] + sm[3];
}

// ---------- launch ----------
extern "C" void kernel_launch(void* const* d_in, const int* in_sizes, int n_in,
                              void* d_out, int out_size, void* d_ws, size_t ws_size,
                              hipStream_t stream) {
  const float* x     = (const float*)d_in[0];
  const float* rfs   = (const float*)d_in[1];
  const float* lw    = (const float*)d_in[2];
  const float* adath = (const float*)d_in[3];
  const float* aenv  = (const float*)d_in[4];
  const float* sre   = (const float*)d_in[5];
  const float* envk  = (const float*)d_in[6];
  const float* mmask = (const float*)d_in[7];

  float* out = (float*)d_out;
  float* out_raw = out;             // 16384
  float* out_lat = out + L;         // 16384
  float* out_cor = out + 2 * L;     // 1
  float* out_xt  = out + 2 * L + 1; // 16384*882

  float* wsf  = (float*)d_ws;
  float* aff  = wsf;
  float* latA = wsf + L;
  float* latC = wsf + 2 * L;
  float* lat2 = wsf + 3 * L;
  float* mean = wsf + 4 * L;
  float* part = wsf + 5 * L;

  dim3 blk(256);
  dim3 grid_wave(L / 4);   // wave-per-pixel kernels: 4 waves/block

  k_xtiles<<<grid_wave, blk, 0, stream>>>(x, rfs, adath, aenv,
                                          out_raw, out_xt, aff, latA, mean);
  for (int it = 0; it < NITER; ++it) {
    k_conv<<<grid_wave, blk, 0, stream>>>(latA, sre, latC);
    k_latneg<<<grid_wave, blk, 0, stream>>>(lw, envk, latC, aff, lat2);
    k_maxnorm<<<grid_wave, blk, 0, stream>>>(lat2, mmask, latA, mean, out_lat,
                                             (it == NITER - 1) ? 1 : 0);
  }
  k_corrpart<<<grid_wave, blk, 0, stream>>>(lw, envk, mean, part);
  k_reduce<<<1, blk, 0, stream>>>(part, out_cor);
}